// Round 7
// baseline (371.365 us; speedup 1.0000x reference)
//
#include <hip/hip_runtime.h>
#include <hip/hip_bf16.h>

typedef unsigned short u16;
typedef unsigned int   u32;
typedef short v8s __attribute__((ext_vector_type(8)));
typedef float v4f __attribute__((ext_vector_type(4)));
typedef float v16f __attribute__((ext_vector_type(16)));

#define MFMA16(a,b,c) __builtin_amdgcn_mfma_f32_16x16x32_bf16(a,b,c,0,0,0)
#define MFMA32(a,b,c) __builtin_amdgcn_mfma_f32_32x32x16_bf16(a,b,c,0,0,0)

__device__ __forceinline__ float b2f(u16 u){ u32 i = ((u32)u)<<16; float f; __builtin_memcpy(&f,&i,4); return f; }
__device__ __forceinline__ u16 f2b(float f){ u32 i; __builtin_memcpy(&i,&f,4); u32 r = (i + 0x7FFFu + ((i>>16)&1u))>>16; return (u16)r; }
__device__ __forceinline__ u32 pk2(float a, float b){
  __hip_bfloat162 h = __float22bfloat162_rn(make_float2(a,b));
  u32 r; __builtin_memcpy(&r,&h,4); return r;
}

// async global->LDS DMA, 16B per lane. dst MUST be wave-uniform base + lane*16B.
__device__ __forceinline__ void gl16(const void* g, void* l){
  __builtin_amdgcn_global_load_lds((const __attribute__((address_space(1))) u32*)g,
                                   (__attribute__((address_space(3))) u32*)l, 16, 0, 0);
}

// fp32 fallback staging (convert 8 f32 -> 8 bf16 into LDS)
__device__ __forceinline__ void stage8f(const float* g, u16* l){
  float4 a = *(const float4*)g, b = *(const float4*)(g+4);
  union { u16 h[8]; uint4 q; } u;
  u.h[0]=f2b(a.x); u.h[1]=f2b(a.y); u.h[2]=f2b(a.z); u.h[3]=f2b(a.w);
  u.h[4]=f2b(b.x); u.h[5]=f2b(b.y); u.h[6]=f2b(b.z); u.h[7]=f2b(b.w);
  *(uint4*)l = u.q;
}
__device__ __forceinline__ float ldscal(const void* base, int i, bool isf32){
  return isf32 ? ((const float*)base)[i] : b2f(((const u16*)base)[i]);
}

// ---------------------------------------------------------------------------
// Kernel 0: dtype detector (insurance; inputs measured bf16 on this harness).
// ---------------------------------------------------------------------------
__global__ void detect_dtype(const u32* __restrict__ q, int* __restrict__ flag){
  __shared__ int cnt;
  if (threadIdx.x==0) cnt = 0;
  __syncthreads();
  int hits = 0;
  for (int i = threadIdx.x; i < 4096; i += 256){
    u32 e = (q[i] >> 7) & 0xFFu;
    if (e >= 118 && e <= 134) hits++;
  }
  atomicAdd(&cnt, hits);
  __syncthreads();
  if (threadIdx.x==0) *flag = (cnt >= 3500) ? 0 : 1;  // 0 = bf16, 1 = fp32
}

// ---------------------------------------------------------------------------
// Kernel 1: fused QKV projection (unchanged from R6).
// ---------------------------------------------------------------------------
__global__ __launch_bounds__(256) void proj_qkv(
    const void* __restrict__ Qx, const void* __restrict__ Kx, const void* __restrict__ Vx,
    const void* __restrict__ WQw, const void* __restrict__ WQb,
    const void* __restrict__ WKw, const void* __restrict__ WKb,
    const void* __restrict__ WVw, const void* __restrict__ WVb,
    u16* __restrict__ Qp, u16* __restrict__ Kp, u16* __restrict__ Vt,
    const int* __restrict__ fl)
{
  __shared__ u16 smem[32768];          // As(16384) + Ws(16384); reused as Cs
  u16* As = smem;
  u16* Ws = smem + 16384;
  const bool isf32 = (*fl != 0);

  const int z = blockIdx.z;
  const void* X    = (z==0) ? Qx  : (z==1 ? Kx  : Vx);
  const void* W    = (z==0) ? WQw : (z==1 ? WKw : WVw);
  const void* bias = (z==0) ? WQb : (z==1 ? WKb : WVb);
  u16* out         = (z==0) ? Qp  : (z==1 ? Kp  : Vt);

  const int tid = threadIdx.x, wv = tid>>6, lane = tid&63;
  const int quad = lane>>4, l16 = lane&15;
  const int r4 = lane>>2, c4 = lane&3;
  const int m0 = blockIdx.x*128, n0 = blockIdx.y*128;

  if (!isf32) {
    const u16* Xb = (const u16*)X;
    const u16* Wb = (const u16*)W;
    for (int idx = wv; idx < 32; idx += 4) {
      int kt = idx >> 3, rg = idx & 7;
      int row = rg*16 + r4;
      gl16(Xb + (size_t)(m0+row)*128 + kt*32 + c4*8, &As[kt*4096 + rg*512 + lane*8]);
      gl16(Wb + (size_t)(n0+row)*128 + kt*32 + c4*8, &Ws[kt*4096 + rg*512 + lane*8]);
    }
  } else {
    const float* Xb = (const float*)X;
    const float* Wb = (const float*)W;
    for (int idx = wv; idx < 32; idx += 4) {
      int kt = idx >> 3, rg = idx & 7;
      int row = rg*16 + r4;
      stage8f(Xb + (size_t)(m0+row)*128 + kt*32 + c4*8, &As[kt*4096 + rg*512 + lane*8]);
      stage8f(Wb + (size_t)(n0+row)*128 + kt*32 + c4*8, &Ws[kt*4096 + rg*512 + lane*8]);
    }
  }
  __syncthreads();

  const int wm = wv & 1, wn = wv >> 1;
  v4f acc[4][4];
#pragma unroll
  for (int i=0;i<4;i++)
#pragma unroll
    for (int j=0;j<4;j++) acc[i][j] = (v4f){0.f,0.f,0.f,0.f};

  if (z < 2) {
#pragma unroll
    for (int ks=0; ks<4; ++ks) {
      v8s af[4], bf[4];
#pragma unroll
      for (int mi=0; mi<4; ++mi) af[mi] = *(const v8s*)&As[ks*4096 + (wm*64+mi*16+l16)*32 + quad*8];
#pragma unroll
      for (int ni=0; ni<4; ++ni) bf[ni] = *(const v8s*)&Ws[ks*4096 + (wn*64+ni*16+l16)*32 + quad*8];
#pragma unroll
      for (int mi=0; mi<4; ++mi)
#pragma unroll
        for (int ni=0; ni<4; ++ni)
          acc[mi][ni] = MFMA16(bf[ni], af[mi], acc[mi][ni]);   // A=W, B=X
    }
#pragma unroll
    for (int ni=0; ni<4; ++ni) {
      int nb = n0 + wn*64 + ni*16 + quad*4;   // global n, 4 consecutive (r)
      float bv0 = ldscal(bias, nb+0, isf32);
      float bv1 = ldscal(bias, nb+1, isf32);
      float bv2 = ldscal(bias, nb+2, isf32);
      float bv3 = ldscal(bias, nb+3, isf32);
      int h = n0 >> 7, dh = nb & 127;
#pragma unroll
      for (int mi=0; mi<4; ++mi) {
        int m = m0 + wm*64 + mi*16 + l16;
        int b = m >> 11, s = m & 2047;
        uint2 pk;
        pk.x = (u32)f2b(acc[mi][ni][0] + bv0) | ((u32)f2b(acc[mi][ni][1] + bv1) << 16);
        pk.y = (u32)f2b(acc[mi][ni][2] + bv2) | ((u32)f2b(acc[mi][ni][3] + bv3) << 16);
        *(uint2*)&out[(size_t)(((b<<3) + h)*2048 + s)*128 + dh] = pk;
      }
    }
  } else {
#pragma unroll
    for (int ks=0; ks<4; ++ks) {
      v8s af[4], bf[4];
#pragma unroll
      for (int mi=0; mi<4; ++mi) af[mi] = *(const v8s*)&As[ks*4096 + (wm*64+mi*16+l16)*32 + quad*8];
#pragma unroll
      for (int ni=0; ni<4; ++ni) bf[ni] = *(const v8s*)&Ws[ks*4096 + (wn*64+ni*16+l16)*32 + quad*8];
#pragma unroll
      for (int mi=0; mi<4; ++mi)
#pragma unroll
        for (int ni=0; ni<4; ++ni)
          acc[mi][ni] = MFMA16(af[mi], bf[ni], acc[mi][ni]);
    }
    __syncthreads();               // all waves done reading As/Ws
    u16* Cs = smem;                // Cs[n][136]
#pragma unroll
    for (int ni=0; ni<4; ++ni) {
      int nl = wn*64 + ni*16 + l16;
      float bv = ldscal(bias, n0 + nl, isf32);
#pragma unroll
      for (int mi=0; mi<4; ++mi) {
        int ml = wm*64 + mi*16 + quad*4;
        uint2 pk;
        pk.x = (u32)f2b(acc[mi][ni][0] + bv) | ((u32)f2b(acc[mi][ni][1] + bv) << 16);
        pk.y = (u32)f2b(acc[mi][ni][2] + bv) | ((u32)f2b(acc[mi][ni][3] + bv) << 16);
        *(uint2*)&Cs[nl*136 + ml] = pk;
      }
    }
    __syncthreads();
    const int nl = tid >> 1;                 // 0..127
    const int mb = (tid & 1) * 64;           // 0 or 64
    const int h = (n0 + nl) >> 7, dh = (n0 + nl) & 127;
    const int b = m0 >> 11, s0 = m0 & 2047;
    size_t gbase = (((size_t)((b<<3) + h)*128 + dh)*2048) + s0 + mb;
    size_t lbase = (size_t)nl*136 + mb;
#pragma unroll
    for (int j = 0; j < 8; ++j)
      *(uint4*)&out[gbase + j*8] = *(const uint4*)&Cs[lbase + j*8];
  }
}

// ---------------------------------------------------------------------------
// Kernel 2: flash attention, 32x32x16 MFMA, XOR-swizzled LDS.
// Physical 16B chunk = ch ^ (row&7): any 8 consecutive rows of a fragment
// read cover all 32 banks (fixes the half-bank-coverage of [row][16] rows).
// Q B-frags loaded direct from global (read-once) -> LDS 48KB -> 3 blocks/CU.
// Fixed-max softmax; denominator via ones-MFMA; XCD swizzle for K/V L2 reuse.
// ---------------------------------------------------------------------------
__global__ __launch_bounds__(256, 3) void attn(
    const u16* __restrict__ Qp, const u16* __restrict__ Kp,
    const u16* __restrict__ Vt, u16* __restrict__ O)
{
  __shared__ u16 Ks[8192];  // [64 key][16 ch], pch = (ch&8)|((ch^key)&7)
  __shared__ u16 Vs[8192];  // [128 d][8 ch],  pch = (ch^d)&7
  __shared__ u16 Ps[8192];  // [128 q][8 ch],  pch = (ch^q)&7

  const int tid = threadIdx.x, wv = tid>>6, lane = tid&63;
  const int l32 = lane&31, h = lane>>5;

  // bits [2:0]=xcd, [6:3]=qi, [8:7]=bh-hi: all 16 q-tiles of a bh on one XCD
  const int n  = blockIdx.x;
  const int bh = (n&7)*4 + (n>>7);
  const int q0 = ((n>>3)&15) * 128;

  const u16* Qb = Qp + (size_t)bh*262144 + (size_t)q0*128;
  const u16* Kb = Kp + (size_t)bh*262144;
  const u16* Vb = Vt + (size_t)bh*262144;

  // Q fragments straight from global: B[n=q][k], q = wv*32+l32, k = kd*16+h*8
  const int qrow = wv*32 + l32;
  v8s qf[8];
#pragma unroll
  for (int kd = 0; kd < 8; ++kd)
    qf[kd] = *(const v8s*)(Qb + qrow*128 + kd*16 + h*8);

  v8s onesf;
#pragma unroll
  for (int j = 0; j < 8; ++j) onesf[j] = (short)0x3F80;  // bf16 1.0

  v16f oacc[4], lacc;
#pragma unroll
  for (int nt = 0; nt < 4; ++nt)
#pragma unroll
    for (int j = 0; j < 16; ++j) oacc[nt][j] = 0.f;
#pragma unroll
  for (int j = 0; j < 16; ++j) lacc[j] = 0.f;

  const float C2 = 0.12751743076f;    // log2(e)/sqrt(128)
  const float CB = -64.0f * C2;       // fixed softmax shift (exact: shift-invariance)
  const int q7 = qrow & 7;

  for (int it = 0; it < 32; ++it) {
#pragma unroll
    for (int r = 0; r < 4; ++r) {     // K tile 64x128 -> Ks, src-chunk swizzle
      int idx = r*256 + tid;
      int key = idx >> 4, pch = idx & 15;
      int ch = (pch & 8) | ((pch ^ key) & 7);
      gl16(Kb + it*8192 + key*128 + ch*8, &Ks[idx*8]);
    }
#pragma unroll
    for (int r = 0; r < 4; ++r) {     // V^T tile 128x64 -> Vs
      int idx = r*256 + tid;
      int d = idx >> 3, pch = idx & 7;
      int ch = (pch ^ d) & 7;
      gl16(Vb + it*64 + (size_t)d*2048 + ch*8, &Vs[idx*8]);
    }
    __syncthreads();

    // S^T (64 keys x 32 q per wave) = K * Q^T
    v16f sa[2];
#pragma unroll
    for (int m = 0; m < 2; ++m)
#pragma unroll
      for (int j = 0; j < 16; ++j) sa[m][j] = 0.f;
#pragma unroll
    for (int kd = 0; kd < 8; ++kd) {
      int ch = kd*2 + h;
#pragma unroll
      for (int m = 0; m < 2; ++m) {
        int key = m*32 + l32;
        int pch = (ch & 8) | ((ch ^ key) & 7);
        v8s kf = *(const v8s*)&Ks[key*128 + pch*8];
        sa[m] = MFMA32(kf, qf[kd], sa[m]);
      }
    }

    // P = exp2(sa*C2 + CB); lane holds keys m*32+g*8+h*4+{0..3} for q=qrow
#pragma unroll
    for (int m = 0; m < 2; ++m) {
#pragma unroll
      for (int g = 0; g < 4; ++g) {
        float p0 = exp2f(fmaf(sa[m][g*4+0], C2, CB));
        float p1 = exp2f(fmaf(sa[m][g*4+1], C2, CB));
        float p2 = exp2f(fmaf(sa[m][g*4+2], C2, CB));
        float p3 = exp2f(fmaf(sa[m][g*4+3], C2, CB));
        int c = m*4 + g;                  // 8-key chunk index
        int pch = (c ^ q7) & 7;
        uint2 pk; pk.x = pk2(p0, p1); pk.y = pk2(p2, p3);
        *(uint2*)&Ps[qrow*64 + pch*8 + h*4] = pk;
      }
    }

    // REQUIRED: P stores visible before fragment reads (same-wave LDS RAW).
    asm volatile("s_waitcnt lgkmcnt(0)" ::: "memory");

    // O(32q x 128d) += P(32q x 64k) @ V(64k x 128d);  l += P @ ones
#pragma unroll
    for (int kt = 0; kt < 4; ++kt) {
      int ch = kt*2 + h;
      int pchp = (ch ^ q7) & 7;
      v8s pf = *(const v8s*)&Ps[qrow*64 + pchp*8];
      lacc = MFMA32(pf, onesf, lacc);
#pragma unroll
      for (int nt = 0; nt < 4; ++nt) {
        int d = nt*32 + l32;
        int pchv = (ch ^ (d & 7)) & 7;
        v8s vf = *(const v8s*)&Vs[d*64 + pchv*8];
        oacc[nt] = MFMA32(pf, vf, oacc[nt]);
      }
    }
    __syncthreads();  // Ks/Vs/Ps consumed; safe to restage
  }

  const int b = bh >> 3, hd = bh & 7;
#pragma unroll
  for (int reg = 0; reg < 16; ++reg) {
    int q = q0 + wv*32 + (reg&3) + 8*(reg>>2) + 4*h;
    float inv = 1.0f / lacc[reg];
    size_t base = ((size_t)(b*2048 + q))*1024 + hd*128;
#pragma unroll
    for (int nt = 0; nt < 4; ++nt)
      O[base + nt*32 + l32] = f2b(oacc[nt][reg] * inv);
  }
}

// ---------------------------------------------------------------------------
// Kernel 3: output projection  out[8192,128] = Ow[8192,1024] @ Ww^T + Wb.
// M-tile 16, grid 512 (2x parallelism). A-frags direct from global (L1-hot,
// shared by all 4 waves); W tile XOR-swizzled in LDS (16KB -> 8 blocks/CU).
// ---------------------------------------------------------------------------
__global__ __launch_bounds__(256) void outproj(
    const u16* __restrict__ A, const void* __restrict__ Ww,
    const void* __restrict__ Wb, void* __restrict__ outv,
    const int* __restrict__ fl)
{
  __shared__ u16 Ws[8192];  // [128 n][8 ch], pch = (ch^n)&7
  const bool isf32 = (*fl != 0);

  const int tid = threadIdx.x, wv = tid>>6, lane = tid&63;
  const int quad = lane>>4, l16 = lane&15;
  const int m0 = blockIdx.x*16;

  v4f acc[2];   // nt = wv*2 + nj
#pragma unroll
  for (int j=0;j<2;j++) acc[j] = (v4f){0.f,0.f,0.f,0.f};

  for (int kb = 0; kb < 1024; kb += 64) {
    if (!isf32) {
      const u16* Wwb = (const u16*)Ww;
#pragma unroll
      for (int r = 0; r < 4; ++r) {
        int idx = r*256 + tid;
        int nn = idx >> 3, pch = idx & 7;
        int ch = (pch ^ nn) & 7;
        gl16(Wwb + (size_t)nn*1024 + kb + ch*8, &Ws[idx*8]);
      }
    } else {
      const float* Wwb = (const float*)Ww;
#pragma unroll
      for (int r = 0; r < 4; ++r) {
        int idx = r*256 + tid;
        int nn = idx >> 3, pch = idx & 7;
        int ch = (pch ^ nn) & 7;
        stage8f(Wwb + (size_t)nn*1024 + kb + ch*8, &Ws[idx*8]);
      }
    }
    __syncthreads();
#pragma unroll
    for (int ks = 0; ks < 2; ++ks) {
      v8s af = *(const v8s*)(A + (size_t)(m0+l16)*1024 + kb + ks*32 + quad*8);
#pragma unroll
      for (int nj = 0; nj < 2; ++nj) {
        int nn = (wv*2+nj)*16 + l16;
        int ch = ks*4 + quad;
        int pch = (ch ^ nn) & 7;
        v8s bf = *(const v8s*)&Ws[nn*64 + pch*8];
        acc[nj] = MFMA16(af, bf, acc[nj]);
      }
    }
    __syncthreads();
  }

#pragma unroll
  for (int nj = 0; nj < 2; ++nj) {
    int col = (wv*2+nj)*16 + l16;
    float bv = ldscal(Wb, col, isf32);
#pragma unroll
    for (int r = 0; r < 4; ++r) {
      int row = m0 + quad*4 + r;
      float v = acc[nj][r] + bv;
      if (isf32) ((float*)outv)[(size_t)row*128 + col] = v;
      else       ((u16*)outv)[(size_t)row*128 + col]   = f2b(v);
    }
  }
}

// ---------------------------------------------------------------------------
extern "C" void kernel_launch(void* const* d_in, const int* in_sizes, int n_in,
                              void* d_out, int out_size, void* d_ws, size_t ws_size,
                              hipStream_t stream) {
  const void* Q   = d_in[0];
  const void* K   = d_in[1];
  const void* V   = d_in[2];
  const void* WQw = d_in[3];
  const void* WQb = d_in[4];
  const void* WKw = d_in[5];
  const void* WKb = d_in[6];
  const void* WVw = d_in[7];
  const void* WVb = d_in[8];
  const void* Ww  = d_in[9];
  const void* Wb  = d_in[10];
  u16* ws = (u16*)d_ws;

  int* flag = (int*)ws;                      // 4 B flag
  const size_t SZ = (size_t)4*8*2048*128;    // 8,388,608 elems per tensor
  u16* Qp = ws + 32;                         // 64 B offset keeps alignment
  u16* Kp = Qp + SZ;
  u16* Vt = Kp + SZ;
  u16* Ow = Vt + SZ;

  hipLaunchKernelGGL(detect_dtype, dim3(1), dim3(256), 0, stream, (const u32*)Q, flag);
  hipLaunchKernelGGL(proj_qkv, dim3(64,8,3), dim3(256), 0, stream,
                     Q,K,V,WQw,WQb,WKw,WKb,WVw,WVb,Qp,Kp,Vt,flag);
  hipLaunchKernelGGL(attn, dim3(512), dim3(256), 0, stream, Qp,Kp,Vt,Ow);
  hipLaunchKernelGGL(outproj, dim3(512), dim3(256), 0, stream, Ow, Ww, Wb, (void*)d_out, flag);
}

// Round 9
// 241.126 us; speedup vs baseline: 1.5401x; 1.5401x over previous
//
#include <hip/hip_runtime.h>
#include <hip/hip_bf16.h>

typedef unsigned short u16;
typedef unsigned int   u32;
typedef short v8s __attribute__((ext_vector_type(8)));
typedef float v4f __attribute__((ext_vector_type(4)));
typedef float v16f __attribute__((ext_vector_type(16)));

#define MFMA16(a,b,c) __builtin_amdgcn_mfma_f32_16x16x32_bf16(a,b,c,0,0,0)
#define MFMA32(a,b,c) __builtin_amdgcn_mfma_f32_32x32x16_bf16(a,b,c,0,0,0)

__device__ __forceinline__ float b2f(u16 u){ u32 i = ((u32)u)<<16; float f; __builtin_memcpy(&f,&i,4); return f; }
__device__ __forceinline__ u16 f2b(float f){ u32 i; __builtin_memcpy(&i,&f,4); u32 r = (i + 0x7FFFu + ((i>>16)&1u))>>16; return (u16)r; }
__device__ __forceinline__ u32 pk2(float a, float b){
  __hip_bfloat162 h = __float22bfloat162_rn(make_float2(a,b));
  u32 r; __builtin_memcpy(&r,&h,4); return r;
}

// async global->LDS DMA, 16B per lane. dst MUST be wave-uniform base + lane*16B.
// Sources must stay lane-contiguous (R7 lesson: permuted sources kill coalescing).
__device__ __forceinline__ void gl16(const void* g, void* l){
  __builtin_amdgcn_global_load_lds((const __attribute__((address_space(1))) u32*)g,
                                   (__attribute__((address_space(3))) u32*)l, 16, 0, 0);
}

// fp32 fallback staging (convert 8 f32 -> 8 bf16 into LDS)
__device__ __forceinline__ void stage8f(const float* g, u16* l){
  float4 a = *(const float4*)g, b = *(const float4*)(g+4);
  union { u16 h[8]; uint4 q; } u;
  u.h[0]=f2b(a.x); u.h[1]=f2b(a.y); u.h[2]=f2b(a.z); u.h[3]=f2b(a.w);
  u.h[4]=f2b(b.x); u.h[5]=f2b(b.y); u.h[6]=f2b(b.z); u.h[7]=f2b(b.w);
  *(uint4*)l = u.q;
}
__device__ __forceinline__ float ldscal(const void* base, int i, bool isf32){
  return isf32 ? ((const float*)base)[i] : b2f(((const u16*)base)[i]);
}

// ---------------------------------------------------------------------------
// Kernel 0: dtype detector (insurance; inputs measured bf16 on this harness).
// ---------------------------------------------------------------------------
__global__ void detect_dtype(const u32* __restrict__ q, int* __restrict__ flag){
  __shared__ int cnt;
  if (threadIdx.x==0) cnt = 0;
  __syncthreads();
  int hits = 0;
  for (int i = threadIdx.x; i < 4096; i += 256){
    u32 e = (q[i] >> 7) & 0xFFu;
    if (e >= 118 && e <= 134) hits++;
  }
  atomicAdd(&cnt, hits);
  __syncthreads();
  if (threadIdx.x==0) *flag = (cnt >= 3500) ? 0 : 1;  // 0 = bf16, 1 = fp32
}

// ---------------------------------------------------------------------------
// Kernel 1: fused QKV projection (R6 version, unchanged).
// ---------------------------------------------------------------------------
__global__ __launch_bounds__(256) void proj_qkv(
    const void* __restrict__ Qx, const void* __restrict__ Kx, const void* __restrict__ Vx,
    const void* __restrict__ WQw, const void* __restrict__ WQb,
    const void* __restrict__ WKw, const void* __restrict__ WKb,
    const void* __restrict__ WVw, const void* __restrict__ WVb,
    u16* __restrict__ Qp, u16* __restrict__ Kp, u16* __restrict__ Vt,
    const int* __restrict__ fl)
{
  __shared__ u16 smem[32768];          // As(16384) + Ws(16384); reused as Cs
  u16* As = smem;
  u16* Ws = smem + 16384;
  const bool isf32 = (*fl != 0);

  const int z = blockIdx.z;
  const void* X    = (z==0) ? Qx  : (z==1 ? Kx  : Vx);
  const void* W    = (z==0) ? WQw : (z==1 ? WKw : WVw);
  const void* bias = (z==0) ? WQb : (z==1 ? WKb : WVb);
  u16* out         = (z==0) ? Qp  : (z==1 ? Kp  : Vt);

  const int tid = threadIdx.x, wv = tid>>6, lane = tid&63;
  const int quad = lane>>4, l16 = lane&15;
  const int r4 = lane>>2, c4 = lane&3;
  const int m0 = blockIdx.x*128, n0 = blockIdx.y*128;

  if (!isf32) {
    const u16* Xb = (const u16*)X;
    const u16* Wb = (const u16*)W;
    for (int idx = wv; idx < 32; idx += 4) {
      int kt = idx >> 3, rg = idx & 7;
      int row = rg*16 + r4;
      gl16(Xb + (size_t)(m0+row)*128 + kt*32 + c4*8, &As[kt*4096 + rg*512 + lane*8]);
      gl16(Wb + (size_t)(n0+row)*128 + kt*32 + c4*8, &Ws[kt*4096 + rg*512 + lane*8]);
    }
  } else {
    const float* Xb = (const float*)X;
    const float* Wb = (const float*)W;
    for (int idx = wv; idx < 32; idx += 4) {
      int kt = idx >> 3, rg = idx & 7;
      int row = rg*16 + r4;
      stage8f(Xb + (size_t)(m0+row)*128 + kt*32 + c4*8, &As[kt*4096 + rg*512 + lane*8]);
      stage8f(Wb + (size_t)(n0+row)*128 + kt*32 + c4*8, &Ws[kt*4096 + rg*512 + lane*8]);
    }
  }
  __syncthreads();

  const int wm = wv & 1, wn = wv >> 1;
  v4f acc[4][4];
#pragma unroll
  for (int i=0;i<4;i++)
#pragma unroll
    for (int j=0;j<4;j++) acc[i][j] = (v4f){0.f,0.f,0.f,0.f};

  if (z < 2) {
#pragma unroll
    for (int ks=0; ks<4; ++ks) {
      v8s af[4], bf[4];
#pragma unroll
      for (int mi=0; mi<4; ++mi) af[mi] = *(const v8s*)&As[ks*4096 + (wm*64+mi*16+l16)*32 + quad*8];
#pragma unroll
      for (int ni=0; ni<4; ++ni) bf[ni] = *(const v8s*)&Ws[ks*4096 + (wn*64+ni*16+l16)*32 + quad*8];
#pragma unroll
      for (int mi=0; mi<4; ++mi)
#pragma unroll
        for (int ni=0; ni<4; ++ni)
          acc[mi][ni] = MFMA16(bf[ni], af[mi], acc[mi][ni]);   // A=W, B=X
    }
#pragma unroll
    for (int ni=0; ni<4; ++ni) {
      int nb = n0 + wn*64 + ni*16 + quad*4;   // global n, 4 consecutive (r)
      float bv0 = ldscal(bias, nb+0, isf32);
      float bv1 = ldscal(bias, nb+1, isf32);
      float bv2 = ldscal(bias, nb+2, isf32);
      float bv3 = ldscal(bias, nb+3, isf32);
      int h = n0 >> 7, dh = nb & 127;
#pragma unroll
      for (int mi=0; mi<4; ++mi) {
        int m = m0 + wm*64 + mi*16 + l16;
        int b = m >> 11, s = m & 2047;
        uint2 pk;
        pk.x = (u32)f2b(acc[mi][ni][0] + bv0) | ((u32)f2b(acc[mi][ni][1] + bv1) << 16);
        pk.y = (u32)f2b(acc[mi][ni][2] + bv2) | ((u32)f2b(acc[mi][ni][3] + bv3) << 16);
        *(uint2*)&out[(size_t)(((b<<3) + h)*2048 + s)*128 + dh] = pk;
      }
    }
  } else {
#pragma unroll
    for (int ks=0; ks<4; ++ks) {
      v8s af[4], bf[4];
#pragma unroll
      for (int mi=0; mi<4; ++mi) af[mi] = *(const v8s*)&As[ks*4096 + (wm*64+mi*16+l16)*32 + quad*8];
#pragma unroll
      for (int ni=0; ni<4; ++ni) bf[ni] = *(const v8s*)&Ws[ks*4096 + (wn*64+ni*16+l16)*32 + quad*8];
#pragma unroll
      for (int mi=0; mi<4; ++mi)
#pragma unroll
        for (int ni=0; ni<4; ++ni)
          acc[mi][ni] = MFMA16(af[mi], bf[ni], acc[mi][ni]);
    }
    __syncthreads();               // all waves done reading As/Ws
    u16* Cs = smem;                // Cs[n][136]
#pragma unroll
    for (int ni=0; ni<4; ++ni) {
      int nl = wn*64 + ni*16 + l16;
      float bv = ldscal(bias, n0 + nl, isf32);
#pragma unroll
      for (int mi=0; mi<4; ++mi) {
        int ml = wm*64 + mi*16 + quad*4;
        uint2 pk;
        pk.x = (u32)f2b(acc[mi][ni][0] + bv) | ((u32)f2b(acc[mi][ni][1] + bv) << 16);
        pk.y = (u32)f2b(acc[mi][ni][2] + bv) | ((u32)f2b(acc[mi][ni][3] + bv) << 16);
        *(uint2*)&Cs[nl*136 + ml] = pk;
      }
    }
    __syncthreads();
    const int nl = tid >> 1;                 // 0..127
    const int mb = (tid & 1) * 64;           // 0 or 64
    const int h = (n0 + nl) >> 7, dh = (n0 + nl) & 127;
    const int b = m0 >> 11, s0 = m0 & 2047;
    size_t gbase = (((size_t)((b<<3) + h)*128 + dh)*2048) + s0 + mb;
    size_t lbase = (size_t)nl*136 + mb;
#pragma unroll
    for (int j = 0; j < 8; ++j)
      *(uint4*)&out[gbase + j*8] = *(const uint4*)&Cs[lbase + j*8];
  }
}

// ---------------------------------------------------------------------------
// Kernel 2: flash attention, 32x32x16 MFMA, R6 layouts + K/V DOUBLE-BUFFER
// PREFETCH: tile it+1's gl16s issue right after the barrier and stay in
// flight through the whole compute of tile it, so the next barrier's vmcnt
// drain is cheap. Buffers selected by integer offsets (NO LDS pointer
// arrays — gfx950 static-initializer limitation, R8 lesson).
// LDS: Ks x2 (16K) + Vs x2 (16K) + Ps 16K = 80KB -> 2 blocks/CU.
// ---------------------------------------------------------------------------
__global__ __launch_bounds__(256, 2) void attn(
    const u16* __restrict__ Qp, const u16* __restrict__ Kp,
    const u16* __restrict__ Vt, u16* __restrict__ O)
{
  __shared__ u16 smem[40960];              // 80 KB
  // layout (u16 offsets): Ks0 @0, Ks1 @8192, Vs0 @16384, Vs1 @24576, Ps @32768
  u16* const Ps = smem + 32768;            // [4 kt][128 q][16]

  const int tid = threadIdx.x, wv = tid>>6, lane = tid&63;
  const int l32 = lane&31, h = lane>>5;

  // bits [2:0]=xcd, [6:3]=qi, [8:7]=bh-hi: all 16 q-tiles of a bh on one XCD
  const int n  = blockIdx.x;
  const int bh = (n&7)*4 + (n>>7);
  const int q0 = ((n>>3)&15) * 128;

  const u16* Qb = Qp + (size_t)bh*262144 + (size_t)q0*128;
  const u16* Kb = Kp + (size_t)bh*262144;
  const u16* Vb = Vt + (size_t)bh*262144;

  // stage Q tile (128x128, 32KB) into the Ks0/Ks1 region, extract B-frags
  for (int r = 0; r < 8; ++r) {
    int idx = r*256 + tid;
    int kd = idx>>8, q = (idx>>1)&127, hh = idx&1;
    gl16(Qb + q*128 + kd*16 + hh*8, &smem[idx*8]);
  }
  __syncthreads();
  const int qrow = wv*32 + l32;
  v8s qf[8];
#pragma unroll
  for (int kd = 0; kd < 8; ++kd)
    qf[kd] = *(const v8s*)&smem[kd*2048 + qrow*16 + h*8];
  __syncthreads();   // Q consumed; Ks buffers free

  v8s onesf;
#pragma unroll
  for (int j = 0; j < 8; ++j) onesf[j] = (short)0x3F80;  // bf16 1.0

  v16f oacc[4], lacc;
#pragma unroll
  for (int nt = 0; nt < 4; ++nt)
#pragma unroll
    for (int j = 0; j < 16; ++j) oacc[nt][j] = 0.f;
#pragma unroll
  for (int j = 0; j < 16; ++j) lacc[j] = 0.f;

  const float C2 = 0.12751743076f;    // log2(e)/sqrt(128)
  const float CB = -64.0f * C2;       // fixed softmax shift (exact: shift-invariance)

  // stage tile 0 into buffer 0
#pragma unroll
  for (int r = 0; r < 4; ++r) {
    int idx = r*256 + tid;
    int kd = idx>>7, key = (idx>>1)&63, hh = idx&1;
    gl16(Kb + key*128 + kd*16 + hh*8, &smem[idx*8]);
  }
#pragma unroll
  for (int r = 0; r < 4; ++r) {
    int idx = r*256 + tid;
    int kt = idx>>8, d = (idx>>1)&127, hh = idx&1;
    gl16(Vb + (size_t)d*2048 + kt*16 + hh*8, &smem[16384 + idx*8]);
  }

  for (int it = 0; it < 32; ++it) {
    const int cur = it & 1;
    const int ko = cur*8192;          // current Ks base (u16 offset)
    const int vo = 16384 + cur*8192;  // current Vs base
    __syncthreads();   // drains stage(it) [in flight since last iter] + all
                       // waves done reading buffer cur from iter it-2

    if (it + 1 < 32) { // prefetch tile it+1 into the other buffer
      const u16* Kt  = Kb + (it+1)*8192;
      const u16* Vtt = Vb + (it+1)*64;
      const int kpo = (cur^1)*8192;
      const int vpo = 16384 + (cur^1)*8192;
#pragma unroll
      for (int r = 0; r < 4; ++r) {
        int idx = r*256 + tid;
        int kd = idx>>7, key = (idx>>1)&63, hh = idx&1;
        gl16(Kt + key*128 + kd*16 + hh*8, &smem[kpo + idx*8]);
      }
#pragma unroll
      for (int r = 0; r < 4; ++r) {
        int idx = r*256 + tid;
        int kt = idx>>8, d = (idx>>1)&127, hh = idx&1;
        gl16(Vtt + (size_t)d*2048 + kt*16 + hh*8, &smem[vpo + idx*8]);
      }
    }

    // S^T (64 keys x 32 q per wave) = K * Q^T
    v16f sa[2];
#pragma unroll
    for (int m = 0; m < 2; ++m)
#pragma unroll
      for (int j = 0; j < 16; ++j) sa[m][j] = 0.f;
#pragma unroll
    for (int kd = 0; kd < 8; ++kd) {
#pragma unroll
      for (int m = 0; m < 2; ++m) {
        v8s kf = *(const v8s*)&smem[ko + kd*1024 + (m*32 + l32)*16 + h*8];
        sa[m] = MFMA32(kf, qf[kd], sa[m]);
      }
    }

    // P = exp2(sa*C2 + CB); lane holds keys m*32+g*8+h*4+{0..3} for q=qrow
#pragma unroll
    for (int m = 0; m < 2; ++m) {
#pragma unroll
      for (int g = 0; g < 4; ++g) {
        float p0 = exp2f(fmaf(sa[m][g*4+0], C2, CB));
        float p1 = exp2f(fmaf(sa[m][g*4+1], C2, CB));
        float p2 = exp2f(fmaf(sa[m][g*4+2], C2, CB));
        float p3 = exp2f(fmaf(sa[m][g*4+3], C2, CB));
        int key0 = m*32 + g*8 + h*4;
        uint2 pk; pk.x = pk2(p0, p1); pk.y = pk2(p2, p3);
        *(uint2*)&Ps[(key0>>4)*2048 + qrow*16 + (key0&15)] = pk;
      }
    }

    // REQUIRED: P stores visible before fragment reads (same-wave LDS RAW).
    asm volatile("s_waitcnt lgkmcnt(0)" ::: "memory");

    // O(32q x 128d) += P(32q x 64k) @ V(64k x 128d);  l += P @ ones
#pragma unroll
    for (int kt = 0; kt < 4; ++kt) {
      v8s pf = *(const v8s*)&Ps[kt*2048 + qrow*16 + h*8];
      lacc = MFMA32(pf, onesf, lacc);
#pragma unroll
      for (int nt = 0; nt < 4; ++nt) {
        v8s vf = *(const v8s*)&smem[vo + kt*2048 + (nt*32 + l32)*16 + h*8];
        oacc[nt] = MFMA32(pf, vf, oacc[nt]);
      }
    }
  }

  const int b = bh >> 3, hd = bh & 7;
#pragma unroll
  for (int reg = 0; reg < 16; ++reg) {
    int q = q0 + wv*32 + (reg&3) + 8*(reg>>2) + 4*h;
    float inv = 1.0f / lacc[reg];
    size_t base = ((size_t)(b*2048 + q))*1024 + hd*128;
#pragma unroll
    for (int nt = 0; nt < 4; ++nt)
      O[base + nt*32 + l32] = f2b(oacc[nt][reg] * inv);
  }
}

// ---------------------------------------------------------------------------
// Kernel 3: output projection (R6 version, unchanged).
// ---------------------------------------------------------------------------
__global__ __launch_bounds__(256) void outproj(
    const u16* __restrict__ A, const void* __restrict__ Ww,
    const void* __restrict__ Wb, void* __restrict__ outv,
    const int* __restrict__ fl)
{
  __shared__ u16 As[2048];  // [2 kt][32 m][32 k]
  __shared__ u16 Ws[8192];  // [2 kt][128 n][32 k]
  const bool isf32 = (*fl != 0);

  const int tid = threadIdx.x, wv = tid>>6, lane = tid&63;
  const int quad = lane>>4, l16 = lane&15;
  const int r4 = lane>>2, c4 = lane&3;
  const int m0 = blockIdx.x*32;

  v4f acc[2][2];   // [mi][nj], nt = wv*2 + nj
#pragma unroll
  for (int i=0;i<2;i++)
#pragma unroll
    for (int j=0;j<2;j++) acc[i][j] = (v4f){0.f,0.f,0.f,0.f};

  for (int kb = 0; kb < 1024; kb += 64) {
    {  // A tile: 4 regions, one per wave
      int kt = wv >> 1, rg = wv & 1;
      int row = rg*16 + r4;
      gl16(A + (size_t)(m0+row)*1024 + kb + kt*32 + c4*8, &As[kt*1024 + rg*512 + lane*8]);
    }
    if (!isf32) {
      const u16* Wwb = (const u16*)Ww;
      for (int idx = wv; idx < 16; idx += 4) {
        int kt = idx >> 3, rg = idx & 7;
        int row = rg*16 + r4;
        gl16(Wwb + (size_t)row*1024 + kb + kt*32 + c4*8, &Ws[kt*4096 + rg*512 + lane*8]);
      }
    } else {
      const float* Wwb = (const float*)Ww;
      for (int idx = wv; idx < 16; idx += 4) {
        int kt = idx >> 3, rg = idx & 7;
        int row = rg*16 + r4;
        stage8f(Wwb + (size_t)row*1024 + kb + kt*32 + c4*8, &Ws[kt*4096 + rg*512 + lane*8]);
      }
    }
    __syncthreads();
#pragma unroll
    for (int ks = 0; ks < 2; ++ks) {
      v8s af0 = *(const v8s*)&As[ks*1024 + (l16)*32 + quad*8];
      v8s af1 = *(const v8s*)&As[ks*1024 + (16 + l16)*32 + quad*8];
#pragma unroll
      for (int nj = 0; nj < 2; ++nj) {
        v8s bf = *(const v8s*)&Ws[ks*4096 + ((wv*2+nj)*16 + l16)*32 + quad*8];
        acc[0][nj] = MFMA16(af0, bf, acc[0][nj]);
        acc[1][nj] = MFMA16(af1, bf, acc[1][nj]);
      }
    }
    __syncthreads();
  }

#pragma unroll
  for (int nj = 0; nj < 2; ++nj) {
    int col = (wv*2+nj)*16 + l16;
    float bv = ldscal(Wb, col, isf32);
#pragma unroll
    for (int mi = 0; mi < 2; ++mi) {
#pragma unroll
      for (int r = 0; r < 4; ++r) {
        int row = m0 + mi*16 + quad*4 + r;
        float v = acc[mi][nj][r] + bv;
        if (isf32) ((float*)outv)[(size_t)row*128 + col] = v;
        else       ((u16*)outv)[(size_t)row*128 + col]   = f2b(v);
      }
    }
  }
}

// ---------------------------------------------------------------------------
extern "C" void kernel_launch(void* const* d_in, const int* in_sizes, int n_in,
                              void* d_out, int out_size, void* d_ws, size_t ws_size,
                              hipStream_t stream) {
  const void* Q   = d_in[0];
  const void* K   = d_in[1];
  const void* V   = d_in[2];
  const void* WQw = d_in[3];
  const void* WQb = d_in[4];
  const void* WKw = d_in[5];
  const void* WKb = d_in[6];
  const void* WVw = d_in[7];
  const void* WVb = d_in[8];
  const void* Ww  = d_in[9];
  const void* Wb  = d_in[10];
  u16* ws = (u16*)d_ws;

  int* flag = (int*)ws;                      // 4 B flag
  const size_t SZ = (size_t)4*8*2048*128;    // 8,388,608 elems per tensor
  u16* Qp = ws + 32;                         // 64 B offset keeps alignment
  u16* Kp = Qp + SZ;
  u16* Vt = Kp + SZ;
  u16* Ow = Vt + SZ;

  hipLaunchKernelGGL(detect_dtype, dim3(1), dim3(256), 0, stream, (const u32*)Q, flag);
  hipLaunchKernelGGL(proj_qkv, dim3(64,8,3), dim3(256), 0, stream,
                     Q,K,V,WQw,WQb,WKw,WKb,WVw,WVb,Qp,Kp,Vt,flag);
  hipLaunchKernelGGL(attn, dim3(512), dim3(256), 0, stream, Qp,Kp,Vt,Ow);
  hipLaunchKernelGGL(outproj, dim3(256), dim3(256), 0, stream, Ow, Ww, Wb, (void*)d_out, flag);
}